// Round 2
// baseline (44990.665 us; speedup 1.0000x reference)
//
#include <hip/hip_runtime.h>
#include <hip/hip_bf16.h>
#include <hip/hip_cooperative_groups.h>
#include <stdint.h>

namespace cg = cooperative_groups;

#define Bn 64
#define Tn 512
#define Hn 1024
#define Ln 4
#define GN 4096   // 4*H
#define KC 2048   // concat K = H (x) + H (h)
#define NDIAG (Tn + Ln - 1)

typedef __attribute__((ext_vector_type(8))) short bf16x8;
typedef __attribute__((ext_vector_type(4))) float f32x4;
typedef __attribute__((ext_vector_type(4))) unsigned short u16x4;

__device__ __forceinline__ unsigned short f2bf(float f) {
  union { float f; unsigned u; } v; v.f = f;
  return (unsigned short)((v.u + 0x7FFFu + ((v.u >> 16) & 1u)) >> 16);
}

__device__ __forceinline__ void gload16(const void* g, void* l) {
  __builtin_amdgcn_global_load_lds((const __attribute__((address_space(1))) void*)g,
                                   (__attribute__((address_space(3))) void*)l, 16, 0, 0);
}

__device__ __forceinline__ float sigmf(float x) { return 1.0f / (1.0f + expf(-x)); }

// ---------------- prep: lengths + stable descending rank ----------------
__global__ void prep_kernel(const int* __restrict__ x, int* __restrict__ len, int* __restrict__ rank) {
  __shared__ int sl[Bn];
  int b = threadIdx.x;
  if (b < Bn) {
    int cnt = 0;
    const int* row = x + (size_t)b * Tn;
    for (int t = 0; t < Tn; ++t) cnt += (row[t] > 0) ? 1 : 0;
    sl[b] = cnt;
  }
  __syncthreads();
  if (b < Bn) {
    int Lb = sl[b], r = 0;
    for (int j = 0; j < Bn; ++j) {
      int lj = sl[j];
      r += ((lj > Lb) || (lj == Lb && j < b)) ? 1 : 0;
    }
    len[b] = Lb;
    rank[b] = r;
  }
}

// ---------------- bias fold: b_ih + b_hh ----------------
__global__ void bias_kernel(const float* __restrict__ bih, const float* __restrict__ bhh,
                            float* __restrict__ bias) {
  int i = blockIdx.x * blockDim.x + threadIdx.x;
  if (i < Ln * GN) bias[i] = bih[i] + bhh[i];
}

// ---------------- cast + permute weights into W_cat block layout ----------------
// Wlay[l][n][k]: n = bn*64 + j, j = strip*16 + hcl  (strip=gate, hcl=low 4 bits of h-col)
// gate row g = strip*1024 + bn*16 + hcl ; k<1024 -> Wih[g][k], k>=1024 -> Whh[g][k-1024]
__global__ __launch_bounds__(256) void cast_w_kernel(const float* __restrict__ Wih,
                                                     const float* __restrict__ Whh,
                                                     unsigned short* __restrict__ Wlay) {
  size_t i = (size_t)blockIdx.x * blockDim.x + threadIdx.x; // (l, n, k4)
  int k4 = (int)(i & 511);
  int n  = (int)((i >> 9) & 4095);
  int l  = (int)(i >> 21);
  int bn = n >> 6, j = n & 63;
  int strip = j >> 4, hcl = j & 15;
  int g = strip * 1024 + bn * 16 + hcl;
  int k = k4 * 4;
  f32x4 v;
  if (k < 1024) v = *(const f32x4*)(Wih + ((size_t)l * GN + g) * Hn + k);
  else          v = *(const f32x4*)(Whh + ((size_t)l * GN + g) * Hn + (k - 1024));
  u16x4 pv;
#pragma unroll
  for (int u = 0; u < 4; ++u) pv[u] = f2bf(v[u]);
  *(u16x4*)(Wlay + i * 4) = pv;
}

// ---------------- embedding gather -> Xemb (T,B,H) bf16 ----------------
__global__ __launch_bounds__(256) void embed_kernel(const int* __restrict__ x,
                                                    const float* __restrict__ emb,
                                                    unsigned short* __restrict__ Xemb) {
  int row = blockIdx.x;        // t*64 + b
  int t = row >> 6, b = row & 63;
  int tok = x[(size_t)b * Tn + t];
  f32x4 v = ((const f32x4*)(emb + (size_t)tok * Hn))[threadIdx.x];
  u16x4 p;
#pragma unroll
  for (int u = 0; u < 4; ++u) p[u] = f2bf(v[u]);
  ((u16x4*)(Xemb + (size_t)row * Hn))[threadIdx.x] = p;
}

// ---------------- init all-layer state (both hmask parities) ----------------
__global__ __launch_bounds__(256) void init_state_kernel(const float* __restrict__ h0,
                                                         const float* __restrict__ c0,
                                                         unsigned short* __restrict__ hmask,
                                                         float* __restrict__ hstate,
                                                         float* __restrict__ cstate) {
  int i = blockIdx.x * blockDim.x + threadIdx.x; // 262144 = L*B*H
  float h = h0[i], c = c0[i];
  hstate[i] = h; cstate[i] = c;
  unsigned short us = f2bf(h);
  hmask[i] = us;
  hmask[Ln * Bn * Hn + i] = us;  // second parity
}

// ---------------- wavefront: 515 diagonals, 4 cells in parallel ----------------
// grid 256 blocks: cell = bid>>6 (= layer), bn = bid&63 (16 h-cols, 4 gate strips)
// per cell: gates[64xB, 64xN] = [in(t), hmask(t-1)](64x2048) @ Wcat_slice(64x2048)^T + bias
__global__ __launch_bounds__(256) void wavefront_kernel(
    const char* __restrict__ Wlay, const float* __restrict__ biasF,
    const char* __restrict__ Xemb,
    unsigned short* __restrict__ hmask, unsigned short* __restrict__ hfresh,
    float* __restrict__ hstate, float* __restrict__ cstate,
    const int* __restrict__ len, float* __restrict__ outp) {
  __shared__ char smem[65536]; // A[64][512B] @0, W[64][512B] @32768
  cg::grid_group grid = cg::this_grid();
  int tid = threadIdx.x, bid = blockIdx.x;
  int cell = bid >> 6, bn = bid & 63;
  int w = tid >> 6, lane = tid & 63, l15 = lane & 15, lk = lane >> 4;
  const char* Wbase = Wlay + ((size_t)(cell * 64 + bn) * 64) * 4096;
  const float* bias = biasF + cell * GN;
  float* cstL = cstate + (size_t)cell * Bn * Hn;
  float* hstL = hstate + (size_t)cell * Bn * Hn;

  for (int d = 0; d < NDIAG; ++d) {
    int t = d - cell;
    if (t >= 0 && t < Tn) {
      int p = d & 1;
      const char* inbase = (cell == 0)
          ? (Xemb + (size_t)t * (Bn * Hn * 2))
          : (const char*)(hfresh + ((size_t)p * Ln + (cell - 1)) * (Bn * Hn));
      const char* hmbase = (const char*)(hmask + ((size_t)p * Ln + cell) * (Bn * Hn));
      unsigned short* hmW = hmask + ((size_t)(p ^ 1) * Ln + cell) * (Bn * Hn);
      unsigned short* hfW = hfresh + ((size_t)(p ^ 1) * Ln + cell) * (Bn * Hn);

      f32x4 acc[4] = {};
      for (int kk = 0; kk < 8; ++kk) {
        const char* abase = (kk < 4) ? (inbase + kk * 512) : (hmbase + (kk - 4) * 512);
        const char* wbase = Wbase + kk * 512;
#pragma unroll
        for (int i = 0; i < 8; ++i) {
          int o = i * 4096 + tid * 16;
          int row = o >> 9;
          int swz = (o & 511) ^ ((row & 31) << 4);   // pre-swizzled source, linear LDS dest
          gload16(abase + (size_t)row * 2048 + swz, smem + o);
        }
#pragma unroll
        for (int i = 0; i < 8; ++i) {
          int o = i * 4096 + tid * 16;
          int row = o >> 9;
          int swz = (o & 511) ^ ((row & 31) << 4);
          gload16(wbase + (size_t)row * 4096 + swz, smem + 32768 + o);
        }
        __syncthreads();
#pragma unroll
        for (int ks = 0; ks < 8; ++ks) {
          int kb = ks * 64 + lk * 16;
          int brow = w * 16 + l15;
          bf16x8 bfr = *(const bf16x8*)(smem + 32768 + brow * 512 + (kb ^ ((brow & 31) << 4)));
#pragma unroll
          for (int mi = 0; mi < 4; ++mi) {
            int arow = mi * 16 + l15;
            bf16x8 afr = *(const bf16x8*)(smem + arow * 512 + (kb ^ ((arow & 31) << 4)));
            acc[mi] = __builtin_amdgcn_mfma_f32_16x16x32_bf16(afr, bfr, acc[mi], 0, 0, 0);
          }
        }
        __syncthreads();
      }
      // gate exchange through LDS: [strip][64][16] f32
      float* smf = (float*)smem;
#pragma unroll
      for (int mi = 0; mi < 4; ++mi)
#pragma unroll
        for (int j = 0; j < 4; ++j)
          smf[w * 1024 + (mi * 16 + lk * 4 + j) * 16 + l15] = acc[mi][j];
      __syncthreads();

      int r = tid >> 2;
      int c0 = (tid & 3) << 2;
      int hc = bn * 16 + c0;
      f32x4 sI = *(const f32x4*)(smf + r * 16 + c0);
      f32x4 sF = *(const f32x4*)(smf + 1024 + r * 16 + c0);
      f32x4 sG = *(const f32x4*)(smf + 2048 + r * 16 + c0);
      f32x4 sO = *(const f32x4*)(smf + 3072 + r * 16 + c0);
      f32x4 bI = *(const f32x4*)(bias + bn * 16 + c0);
      f32x4 bF = *(const f32x4*)(bias + 1024 + bn * 16 + c0);
      f32x4 bG = *(const f32x4*)(bias + 2048 + bn * 16 + c0);
      f32x4 bO = *(const f32x4*)(bias + 3072 + bn * 16 + c0);
      f32x4 cold = *(const f32x4*)(cstL + (size_t)r * Hn + hc);
      f32x4 hold = *(const f32x4*)(hstL + (size_t)r * Hn + hc);
      bool msk = (t < len[r]);
      f32x4 cn, hn, hx;
#pragma unroll
      for (int u = 0; u < 4; ++u) {
        float iv = sigmf(sI[u] + bI[u]);
        float fv = sigmf(sF[u] + bF[u]);
        float gv = tanhf(sG[u] + bG[u]);
        float ov = sigmf(sO[u] + bO[u]);
        float cc = fv * cold[u] + iv * gv;
        float hh = ov * tanhf(cc);
        hx[u] = hh;                      // fresh h -> layer above
        cn[u] = msk ? cc : cold[u];      // frozen-state semantics
        hn[u] = msk ? hh : hold[u];
      }
      *(f32x4*)(cstL + (size_t)r * Hn + hc) = cn;
      *(f32x4*)(hstL + (size_t)r * Hn + hc) = hn;
      u16x4 hb, xb;
#pragma unroll
      for (int u = 0; u < 4; ++u) { hb[u] = f2bf(hn[u]); xb[u] = f2bf(hx[u]); }
      *(u16x4*)(hmW + (size_t)r * Hn + hc) = hb;
      *(u16x4*)(hfW + (size_t)r * Hn + hc) = xb;
      if (cell == Ln - 1) {
        f32x4 o4;
#pragma unroll
        for (int u = 0; u < 4; ++u) o4[u] = msk ? hx[u] : 0.0f;
        *(f32x4*)(outp + ((size_t)r * Tn + t) * Hn + hc) = o4;
      }
    }
    __threadfence();   // device-scope release before cross-XCD consumption
    grid.sync();
  }
}

// ---------------- final state writeback with rank permutation ----------------
__global__ __launch_bounds__(256) void finalize_kernel(const float* __restrict__ hstate,
                                                       const float* __restrict__ cstate,
                                                       const int* __restrict__ rank,
                                                       float* __restrict__ hF, float* __restrict__ cF) {
  int i = blockIdx.x * blockDim.x + threadIdx.x; // 262144
  int l = i >> 16, rem = i & 65535, b = rem >> 10, k = rem & 1023;
  int rb = rank[b];
  hF[((size_t)l * Bn + rb) * Hn + k] = hstate[i];
  cF[((size_t)l * Bn + rb) * Hn + k] = cstate[i];
}

extern "C" void kernel_launch(void* const* d_in, const int* in_sizes, int n_in,
                              void* d_out, int out_size, void* d_ws, size_t ws_size,
                              hipStream_t stream) {
  const int*   x   = (const int*)d_in[0];
  const float* h0  = (const float*)d_in[1];
  const float* c0  = (const float*)d_in[2];
  const float* emb = (const float*)d_in[3];
  const float* Wih = (const float*)d_in[4];
  const float* Whh = (const float*)d_in[5];
  const float* bih = (const float*)d_in[6];
  const float* bhh = (const float*)d_in[7];
  float* out = (float*)d_out;

  char* ws = (char*)d_ws;
  unsigned short* Wlay  = (unsigned short*)ws;                   // 67108864 B
  float*          biasF = (float*)(ws + 67108864);               // 65536 B
  unsigned short* Xemb  = (unsigned short*)(ws + 67174400);      // 67108864 B
  unsigned short* hmask = (unsigned short*)(ws + 134283264);     // 1048576 B (2 parities)
  unsigned short* hfresh= (unsigned short*)(ws + 135331840);     // 1048576 B
  float*          hstate= (float*)(ws + 136380416);              // 1048576 B
  float*          cstate= (float*)(ws + 137428992);              // 1048576 B
  int*            leni  = (int*)(ws + 138477568);
  int*            ranki = (int*)(ws + 138477824);

  prep_kernel<<<1, 64, 0, stream>>>(x, leni, ranki);
  bias_kernel<<<64, 256, 0, stream>>>(bih, bhh, biasF);
  cast_w_kernel<<<32768, 256, 0, stream>>>(Wih, Whh, Wlay);
  embed_kernel<<<Tn * Bn, 256, 0, stream>>>(x, emb, Xemb);
  init_state_kernel<<<1024, 256, 0, stream>>>(h0, c0, hmask, hstate, cstate);

  {
    const char* WlayC = (const char*)Wlay;
    const char* XembC = (const char*)Xemb;
    void* args[] = { (void*)&WlayC, (void*)&biasF, (void*)&XembC,
                     (void*)&hmask, (void*)&hfresh, (void*)&hstate, (void*)&cstate,
                     (void*)&leni, (void*)&out };
    hipLaunchCooperativeKernel((void*)wavefront_kernel, dim3(256), dim3(256),
                               args, 0, stream);
  }

  float* hFbase = out + (size_t)Bn * Tn * Hn;
  float* cFbase = hFbase + (size_t)Ln * Bn * Hn;
  finalize_kernel<<<1024, 256, 0, stream>>>(hstate, cstate, ranki, hFbase, cFbase);
}

// Round 4
// 39669.016 us; speedup vs baseline: 1.1342x; 1.1342x over previous
//
#include <hip/hip_runtime.h>
#include <hip/hip_bf16.h>
#include <hip/hip_cooperative_groups.h>
#include <stdint.h>

namespace cg = cooperative_groups;

#define Bn 64
#define Tn 512
#define Hn 1024
#define Ln 4
#define GN 4096   // 4*H
#define NDIAG (Tn + Ln - 1)
#define DONE_MAGIC 0x00C0FFEE

typedef __attribute__((ext_vector_type(8))) short bf16x8;
typedef __attribute__((ext_vector_type(4))) float f32x4;
typedef __attribute__((ext_vector_type(4))) unsigned short u16x4;

__device__ __forceinline__ unsigned short f2bf(float f) {
  union { float f; unsigned u; } v; v.f = f;
  return (unsigned short)((v.u + 0x7FFFu + ((v.u >> 16) & 1u)) >> 16);
}

__device__ __forceinline__ void gload16(const void* g, void* l) {
  __builtin_amdgcn_global_load_lds((const __attribute__((address_space(1))) void*)g,
                                   (__attribute__((address_space(3))) void*)l, 16, 0, 0);
}

__device__ __forceinline__ float sigmf(float x) { return 1.0f / (1.0f + expf(-x)); }

// ---------------- prep: lengths + stable descending rank + flag reset ----------------
__global__ void prep_kernel(const int* __restrict__ x, int* __restrict__ len,
                            int* __restrict__ rank, int* __restrict__ flag) {
  __shared__ int sl[Bn];
  int b = threadIdx.x;
  if (b == 0) *flag = 0;          // reset done-flag every call (deterministic)
  if (b < Bn) {
    int cnt = 0;
    const int* row = x + (size_t)b * Tn;
    for (int t = 0; t < Tn; ++t) cnt += (row[t] > 0) ? 1 : 0;
    sl[b] = cnt;
  }
  __syncthreads();
  if (b < Bn) {
    int Lb = sl[b], r = 0;
    for (int j = 0; j < Bn; ++j) {
      int lj = sl[j];
      r += ((lj > Lb) || (lj == Lb && j < b)) ? 1 : 0;
    }
    len[b] = Lb;
    rank[b] = r;
  }
}

// ---------------- bias fold ----------------
__global__ void bias_kernel(const float* __restrict__ bih, const float* __restrict__ bhh,
                            float* __restrict__ bias) {
  int i = blockIdx.x * blockDim.x + threadIdx.x;
  if (i < Ln * GN) bias[i] = bih[i] + bhh[i];
}

// ---------------- cast + permute weights into W_cat block layout ----------------
__global__ __launch_bounds__(256) void cast_w_kernel(const float* __restrict__ Wih,
                                                     const float* __restrict__ Whh,
                                                     unsigned short* __restrict__ Wlay) {
  size_t i = (size_t)blockIdx.x * blockDim.x + threadIdx.x; // (l, n, k4)
  int k4 = (int)(i & 511);
  int n  = (int)((i >> 9) & 4095);
  int l  = (int)(i >> 21);
  int bn = n >> 6, j = n & 63;
  int strip = j >> 4, hcl = j & 15;
  int g = strip * 1024 + bn * 16 + hcl;
  int k = k4 * 4;
  f32x4 v;
  if (k < 1024) v = *(const f32x4*)(Wih + ((size_t)l * GN + g) * Hn + k);
  else          v = *(const f32x4*)(Whh + ((size_t)l * GN + g) * Hn + (k - 1024));
  u16x4 pv;
#pragma unroll
  for (int u = 0; u < 4; ++u) pv[u] = f2bf(v[u]);
  *(u16x4*)(Wlay + i * 4) = pv;
}

// ---------------- embedding gather ----------------
__global__ __launch_bounds__(256) void embed_kernel(const int* __restrict__ x,
                                                    const float* __restrict__ emb,
                                                    unsigned short* __restrict__ Xemb) {
  int row = blockIdx.x;        // t*64 + b
  int t = row >> 6, b = row & 63;
  int tok = x[(size_t)b * Tn + t];
  f32x4 v = ((const f32x4*)(emb + (size_t)tok * Hn))[threadIdx.x];
  u16x4 p;
#pragma unroll
  for (int u = 0; u < 4; ++u) p[u] = f2bf(v[u]);
  ((u16x4*)(Xemb + (size_t)row * Hn))[threadIdx.x] = p;
}

// ---------------- init hmask (both parities) ----------------
__global__ __launch_bounds__(256) void init_hmask_kernel(const float* __restrict__ h0,
                                                         unsigned short* __restrict__ hmask) {
  int i = blockIdx.x * blockDim.x + threadIdx.x;
  unsigned short us = f2bf(h0[i]);
  hmask[i] = us;
  hmask[Ln * Bn * Hn + i] = us;
}

// ---------------- init f32 state arrays (fallback path state) ----------------
__global__ __launch_bounds__(256) void init_state_kernel(const float* __restrict__ h0,
                                                         const float* __restrict__ c0,
                                                         float* __restrict__ hstate,
                                                         float* __restrict__ cstate) {
  int i = blockIdx.x * blockDim.x + threadIdx.x;
  hstate[i] = h0[i];
  cstate[i] = c0[i];
}

// ================= PRIMARY: persistent wavefront, W in registers =================
__global__ __launch_bounds__(256, 1) void wavefront_kernel(
    const char* __restrict__ Wlay, const float* __restrict__ biasF,
    const char* __restrict__ Xemb,
    unsigned short* __restrict__ hmask, unsigned short* __restrict__ hfresh,
    const int* __restrict__ len, const int* __restrict__ rankp,
    const float* __restrict__ h0, const float* __restrict__ c0,
    float* __restrict__ outp, float* __restrict__ hF, float* __restrict__ cF,
    int* __restrict__ flag) {
  __shared__ char smem[65536];
  cg::grid_group grid = cg::this_grid();
  int tid = threadIdx.x, bid = blockIdx.x;
  int cell = bid >> 6, bn = bid & 63;
  int w = tid >> 6, lane = tid & 63, l15 = lane & 15, lk = lane >> 4;

  // one-time W preload: 256 KB/block -> 256 VGPR/thread
  bf16x8 wreg[64];
  {
    const char* wrow = Wlay + ((size_t)((cell * 64 + bn) * 64 + w * 16 + l15)) * 4096 + lk * 16;
#pragma unroll
    for (int i = 0; i < 64; ++i)
      wreg[i] = *(const bf16x8*)(wrow + i * 64);
  }

  int r = tid >> 2;
  int c0i = (tid & 3) << 2;
  int hc = bn * 16 + c0i;
  const float* bias = biasF + cell * GN;
  f32x4 bI = *(const f32x4*)(bias + hc);
  f32x4 bF = *(const f32x4*)(bias + 1024 + hc);
  f32x4 bG = *(const f32x4*)(bias + 2048 + hc);
  f32x4 bO = *(const f32x4*)(bias + 3072 + hc);
  int lenr = len[r];
  int rnkr = rankp[r];
  f32x4 hold = *(const f32x4*)(h0 + ((size_t)cell * Bn + r) * Hn + hc);
  f32x4 cold = *(const f32x4*)(c0 + ((size_t)cell * Bn + r) * Hn + hc);

#define STAGE(BUFO, BASE)                                                     \
  {                                                                           \
    _Pragma("unroll")                                                         \
    for (int i_ = 0; i_ < 8; ++i_) {                                          \
      int o_ = i_ * 4096 + tid * 16;                                          \
      int row_ = o_ >> 9, win_ = o_ & 511;                                    \
      gload16((BASE) + (size_t)row_ * 2048 + (win_ ^ ((row_ & 7) << 4)),      \
              smem + (BUFO) + o_);                                            \
    }                                                                         \
  }

  for (int d = 0; d < NDIAG; ++d) {
    int t = d - cell;
    if (t >= 0 && t < Tn) {
      int p = d & 1;
      const char* inbase = (cell == 0)
          ? (Xemb + (size_t)t * (Bn * Hn * 2))
          : (const char*)(hfresh + ((size_t)p * Ln + (cell - 1)) * (Bn * Hn));
      const char* hmbase = (const char*)(hmask + ((size_t)p * Ln + cell) * (Bn * Hn));
      unsigned short* hmW = hmask + ((size_t)(p ^ 1) * Ln + cell) * (Bn * Hn);
      unsigned short* hfW = hfresh + ((size_t)(p ^ 1) * Ln + cell) * (Bn * Hn);

      f32x4 acc[4] = {};
      STAGE(0, inbase);
#pragma unroll
      for (int kc = 0; kc < 8; ++kc) {
        __syncthreads();
        if (kc < 7) {
          const char* nb = (kc + 1 < 4) ? (inbase + (kc + 1) * 512)
                                        : (hmbase + (kc + 1 - 4) * 512);
          STAGE(((kc + 1) & 1) * 32768, nb);
        }
        int bufo = (kc & 1) * 32768;
#pragma unroll
        for (int ksl = 0; ksl < 8; ++ksl) {
          int kb = ksl * 64 + lk * 16;
#pragma unroll
          for (int mi = 0; mi < 4; ++mi) {
            int row = mi * 16 + l15;
            bf16x8 afr = *(const bf16x8*)(smem + bufo + row * 512 + (kb ^ ((row & 7) << 4)));
            acc[mi] = __builtin_amdgcn_mfma_f32_16x16x32_bf16(afr, wreg[kc * 8 + ksl],
                                                              acc[mi], 0, 0, 0);
          }
        }
      }

      float* smf = (float*)smem;
#pragma unroll
      for (int mi = 0; mi < 4; ++mi)
#pragma unroll
        for (int j = 0; j < 4; ++j)
          smf[w * 1024 + (mi * 16 + lk * 4 + j) * 16 + l15] = acc[mi][j];
      __syncthreads();

      f32x4 sI = *(const f32x4*)(smf + r * 16 + c0i);
      f32x4 sF = *(const f32x4*)(smf + 1024 + r * 16 + c0i);
      f32x4 sG = *(const f32x4*)(smf + 2048 + r * 16 + c0i);
      f32x4 sO = *(const f32x4*)(smf + 3072 + r * 16 + c0i);
      bool msk = (t < lenr);
      f32x4 hx;
#pragma unroll
      for (int u = 0; u < 4; ++u) {
        float iv = sigmf(sI[u] + bI[u]);
        float fv = sigmf(sF[u] + bF[u]);
        float gv = tanhf(sG[u] + bG[u]);
        float ov = sigmf(sO[u] + bO[u]);
        float cc = fv * cold[u] + iv * gv;
        float hh = ov * tanhf(cc);
        hx[u] = hh;
        cold[u] = msk ? cc : cold[u];
        hold[u] = msk ? hh : hold[u];
      }
      u16x4 hb, xb;
#pragma unroll
      for (int u = 0; u < 4; ++u) { hb[u] = f2bf(hold[u]); xb[u] = f2bf(hx[u]); }
      *(u16x4*)(hmW + (size_t)r * Hn + hc) = hb;
      *(u16x4*)(hfW + (size_t)r * Hn + hc) = xb;
      if (cell == Ln - 1) {
        f32x4 o4;
#pragma unroll
        for (int u = 0; u < 4; ++u) o4[u] = msk ? hx[u] : 0.0f;
        *(f32x4*)(outp + ((size_t)r * Tn + t) * Hn + hc) = o4;
      }
    }
    __threadfence();
    grid.sync();
  }

  *(f32x4*)(hF + ((size_t)cell * Bn + rnkr) * Hn + hc) = hold;
  *(f32x4*)(cF + ((size_t)cell * Bn + rnkr) * Hn + hc) = cold;
  if (bid == 0 && tid == 0) *flag = DONE_MAGIC;
#undef STAGE
}

// ================= FALLBACK: one diagonal per launch (r2's proven body) =================
__global__ __launch_bounds__(256) void diag_fb_kernel(
    int d, const int* __restrict__ flag,
    const char* __restrict__ Wlay, const float* __restrict__ biasF,
    const char* __restrict__ Xemb,
    unsigned short* __restrict__ hmask, unsigned short* __restrict__ hfresh,
    float* __restrict__ hstate, float* __restrict__ cstate,
    const int* __restrict__ len, float* __restrict__ outp) {
  if (*flag == DONE_MAGIC) return;   // primary path succeeded: no-op
  __shared__ char smem[65536];
  int tid = threadIdx.x, bid = blockIdx.x;
  int cell = bid >> 6, bn = bid & 63;
  int t = d - cell;
  if (t < 0 || t >= Tn) return;
  int w = tid >> 6, lane = tid & 63, l15 = lane & 15, lk = lane >> 4;
  const char* Wbase = Wlay + ((size_t)(cell * 64 + bn) * 64) * 4096;
  const float* bias = biasF + cell * GN;
  float* cstL = cstate + (size_t)cell * Bn * Hn;
  float* hstL = hstate + (size_t)cell * Bn * Hn;

  int p = d & 1;
  const char* inbase = (cell == 0)
      ? (Xemb + (size_t)t * (Bn * Hn * 2))
      : (const char*)(hfresh + ((size_t)p * Ln + (cell - 1)) * (Bn * Hn));
  const char* hmbase = (const char*)(hmask + ((size_t)p * Ln + cell) * (Bn * Hn));
  unsigned short* hmW = hmask + ((size_t)(p ^ 1) * Ln + cell) * (Bn * Hn);
  unsigned short* hfW = hfresh + ((size_t)(p ^ 1) * Ln + cell) * (Bn * Hn);

  f32x4 acc[4] = {};
  for (int kk = 0; kk < 8; ++kk) {
    const char* abase = (kk < 4) ? (inbase + kk * 512) : (hmbase + (kk - 4) * 512);
    const char* wbase = Wbase + kk * 512;
#pragma unroll
    for (int i = 0; i < 8; ++i) {
      int o = i * 4096 + tid * 16;
      int row = o >> 9;
      int swz = (o & 511) ^ ((row & 31) << 4);
      gload16(abase + (size_t)row * 2048 + swz, smem + o);
    }
#pragma unroll
    for (int i = 0; i < 8; ++i) {
      int o = i * 4096 + tid * 16;
      int row = o >> 9;
      int swz = (o & 511) ^ ((row & 31) << 4);
      gload16(wbase + (size_t)row * 4096 + swz, smem + 32768 + o);
    }
    __syncthreads();
#pragma unroll
    for (int ks = 0; ks < 8; ++ks) {
      int kb = ks * 64 + lk * 16;
      int brow = w * 16 + l15;
      bf16x8 bfr = *(const bf16x8*)(smem + 32768 + brow * 512 + (kb ^ ((brow & 31) << 4)));
#pragma unroll
      for (int mi = 0; mi < 4; ++mi) {
        int arow = mi * 16 + l15;
        bf16x8 afr = *(const bf16x8*)(smem + arow * 512 + (kb ^ ((arow & 31) << 4)));
        acc[mi] = __builtin_amdgcn_mfma_f32_16x16x32_bf16(afr, bfr, acc[mi], 0, 0, 0);
      }
    }
    __syncthreads();
  }
  float* smf = (float*)smem;
#pragma unroll
  for (int mi = 0; mi < 4; ++mi)
#pragma unroll
    for (int j = 0; j < 4; ++j)
      smf[w * 1024 + (mi * 16 + lk * 4 + j) * 16 + l15] = acc[mi][j];
  __syncthreads();

  int r = tid >> 2;
  int c0i = (tid & 3) << 2;
  int hc = bn * 16 + c0i;
  f32x4 sI = *(const f32x4*)(smf + r * 16 + c0i);
  f32x4 sF = *(const f32x4*)(smf + 1024 + r * 16 + c0i);
  f32x4 sG = *(const f32x4*)(smf + 2048 + r * 16 + c0i);
  f32x4 sO = *(const f32x4*)(smf + 3072 + r * 16 + c0i);
  f32x4 bI = *(const f32x4*)(bias + hc);
  f32x4 bF = *(const f32x4*)(bias + 1024 + hc);
  f32x4 bG = *(const f32x4*)(bias + 2048 + hc);
  f32x4 bO = *(const f32x4*)(bias + 3072 + hc);
  f32x4 cold = *(const f32x4*)(cstL + (size_t)r * Hn + hc);
  f32x4 hold = *(const f32x4*)(hstL + (size_t)r * Hn + hc);
  bool msk = (t < len[r]);
  f32x4 cn, hn, hx;
#pragma unroll
  for (int u = 0; u < 4; ++u) {
    float iv = sigmf(sI[u] + bI[u]);
    float fv = sigmf(sF[u] + bF[u]);
    float gv = tanhf(sG[u] + bG[u]);
    float ov = sigmf(sO[u] + bO[u]);
    float cc = fv * cold[u] + iv * gv;
    float hh = ov * tanhf(cc);
    hx[u] = hh;
    cn[u] = msk ? cc : cold[u];
    hn[u] = msk ? hh : hold[u];
  }
  *(f32x4*)(cstL + (size_t)r * Hn + hc) = cn;
  *(f32x4*)(hstL + (size_t)r * Hn + hc) = hn;
  u16x4 hb, xb;
#pragma unroll
  for (int u = 0; u < 4; ++u) { hb[u] = f2bf(hn[u]); xb[u] = f2bf(hx[u]); }
  *(u16x4*)(hmW + (size_t)r * Hn + hc) = hb;
  *(u16x4*)(hfW + (size_t)r * Hn + hc) = xb;
  if (cell == Ln - 1) {
    f32x4 o4;
#pragma unroll
    for (int u = 0; u < 4; ++u) o4[u] = msk ? hx[u] : 0.0f;
    *(f32x4*)(outp + ((size_t)r * Tn + t) * Hn + hc) = o4;
  }
}

// ---------------- fallback finalize (flag-guarded) ----------------
__global__ __launch_bounds__(256) void fb_finalize_kernel(
    const int* __restrict__ flag,
    const float* __restrict__ hstate, const float* __restrict__ cstate,
    const int* __restrict__ rank,
    float* __restrict__ hF, float* __restrict__ cF) {
  if (*flag == DONE_MAGIC) return;
  int i = blockIdx.x * blockDim.x + threadIdx.x; // 262144
  int l = i >> 16, rem = i & 65535, b = rem >> 10, k = rem & 1023;
  int rb = rank[b];
  hF[((size_t)l * Bn + rb) * Hn + k] = hstate[i];
  cF[((size_t)l * Bn + rb) * Hn + k] = cstate[i];
}

extern "C" void kernel_launch(void* const* d_in, const int* in_sizes, int n_in,
                              void* d_out, int out_size, void* d_ws, size_t ws_size,
                              hipStream_t stream) {
  const int*   x   = (const int*)d_in[0];
  const float* h0  = (const float*)d_in[1];
  const float* c0  = (const float*)d_in[2];
  const float* emb = (const float*)d_in[3];
  const float* Wih = (const float*)d_in[4];
  const float* Whh = (const float*)d_in[5];
  const float* bih = (const float*)d_in[6];
  const float* bhh = (const float*)d_in[7];
  float* out = (float*)d_out;

  char* ws = (char*)d_ws;
  unsigned short* Wlay  = (unsigned short*)ws;                   // 67108864 B
  float*          biasF = (float*)(ws + 67108864);               // 65536 B
  unsigned short* Xemb  = (unsigned short*)(ws + 67174400);      // 67108864 B
  unsigned short* hmask = (unsigned short*)(ws + 134283264);     // 1048576 B
  unsigned short* hfresh= (unsigned short*)(ws + 135331840);     // 1048576 B
  float*          hstate= (float*)(ws + 136380416);              // 1048576 B
  float*          cstate= (float*)(ws + 137428992);              // 1048576 B
  int*            leni  = (int*)(ws + 138477568);
  int*            ranki = (int*)(ws + 138477824);
  int*            flag  = (int*)(ws + 138478080);

  prep_kernel<<<1, 64, 0, stream>>>(x, leni, ranki, flag);
  bias_kernel<<<64, 256, 0, stream>>>(bih, bhh, biasF);
  cast_w_kernel<<<32768, 256, 0, stream>>>(Wih, Whh, Wlay);
  embed_kernel<<<Tn * Bn, 256, 0, stream>>>(x, emb, Xemb);
  init_hmask_kernel<<<1024, 256, 0, stream>>>(h0, hmask);
  init_state_kernel<<<1024, 256, 0, stream>>>(h0, c0, hstate, cstate);

  float* hFbase = out + (size_t)Bn * Tn * Hn;
  float* cFbase = hFbase + (size_t)Ln * Bn * Hn;

  {
    const char* WlayC = (const char*)Wlay;
    const char* XembC = (const char*)Xemb;
    void* args[] = { (void*)&WlayC, (void*)&biasF, (void*)&XembC,
                     (void*)&hmask, (void*)&hfresh, (void*)&leni, (void*)&ranki,
                     (void*)&h0, (void*)&c0, (void*)&out,
                     (void*)&hFbase, (void*)&cFbase, (void*)&flag };
    hipLaunchCooperativeKernel((void*)wavefront_kernel, dim3(256), dim3(256),
                               args, 0, stream);
  }

  // flag-guarded fallback chain (no-ops if the cooperative kernel ran)
  for (int d = 0; d < NDIAG; ++d) {
    diag_fb_kernel<<<256, 256, 0, stream>>>(d, flag, (const char*)Wlay, biasF,
                                            (const char*)Xemb, hmask, hfresh,
                                            hstate, cstate, leni, out);
  }
  fb_finalize_kernel<<<1024, 256, 0, stream>>>(flag, hstate, cstate, ranki,
                                               hFbase, cFbase);
}

// Round 5
// 16074.805 us; speedup vs baseline: 2.7988x; 2.4678x over previous
//
#include <hip/hip_runtime.h>
#include <hip/hip_bf16.h>
#include <stdint.h>

#define Bn 64
#define Tn 512
#define Hn 1024
#define Ln 4
#define GN 4096   // 4*H
#define NDIAG (Tn + Ln - 1)

typedef __attribute__((ext_vector_type(8))) short bf16x8;
typedef __attribute__((ext_vector_type(4))) float f32x4;
typedef __attribute__((ext_vector_type(4))) unsigned short u16x4;

__device__ __forceinline__ unsigned short f2bf(float f) {
  union { float f; unsigned u; } v; v.f = f;
  return (unsigned short)((v.u + 0x7FFFu + ((v.u >> 16) & 1u)) >> 16);
}

__device__ __forceinline__ void gload16(const void* g, void* l) {
  __builtin_amdgcn_global_load_lds((const __attribute__((address_space(1))) void*)g,
                                   (__attribute__((address_space(3))) void*)l, 16, 0, 0);
}

__device__ __forceinline__ float sigmf(float x) { return 1.0f / (1.0f + expf(-x)); }

// ---------------- prep: lengths + stable descending rank + barrier reset ----------------
__global__ void prep_kernel(const int* __restrict__ x, int* __restrict__ len,
                            int* __restrict__ rank, int* __restrict__ barc,
                            int* __restrict__ barg) {
  __shared__ int sl[Bn];
  int b = threadIdx.x;
  if (b == 0) { *barc = 0; *barg = 0; }   // deterministic barrier state each call
  if (b < Bn) {
    int cnt = 0;
    const int* row = x + (size_t)b * Tn;
    for (int t = 0; t < Tn; ++t) cnt += (row[t] > 0) ? 1 : 0;
    sl[b] = cnt;
  }
  __syncthreads();
  if (b < Bn) {
    int Lb = sl[b], r = 0;
    for (int j = 0; j < Bn; ++j) {
      int lj = sl[j];
      r += ((lj > Lb) || (lj == Lb && j < b)) ? 1 : 0;
    }
    len[b] = Lb;
    rank[b] = r;
  }
}

// ---------------- bias fold ----------------
__global__ void bias_kernel(const float* __restrict__ bih, const float* __restrict__ bhh,
                            float* __restrict__ bias) {
  int i = blockIdx.x * blockDim.x + threadIdx.x;
  if (i < Ln * GN) bias[i] = bih[i] + bhh[i];
}

// ---------------- cast + permute weights into W_cat block layout ----------------
// Wlay[l][n][k]: n = bn*64 + j, j = strip*16 + hcl
// gate row g = strip*1024 + bn*16 + hcl ; k<1024 -> Wih[g][k], k>=1024 -> Whh[g][k-1024]
__global__ __launch_bounds__(256) void cast_w_kernel(const float* __restrict__ Wih,
                                                     const float* __restrict__ Whh,
                                                     unsigned short* __restrict__ Wlay) {
  size_t i = (size_t)blockIdx.x * blockDim.x + threadIdx.x; // (l, n, k4)
  int k4 = (int)(i & 511);
  int n  = (int)((i >> 9) & 4095);
  int l  = (int)(i >> 21);
  int bn = n >> 6, j = n & 63;
  int strip = j >> 4, hcl = j & 15;
  int g = strip * 1024 + bn * 16 + hcl;
  int k = k4 * 4;
  f32x4 v;
  if (k < 1024) v = *(const f32x4*)(Wih + ((size_t)l * GN + g) * Hn + k);
  else          v = *(const f32x4*)(Whh + ((size_t)l * GN + g) * Hn + (k - 1024));
  u16x4 pv;
#pragma unroll
  for (int u = 0; u < 4; ++u) pv[u] = f2bf(v[u]);
  *(u16x4*)(Wlay + i * 4) = pv;
}

// ---------------- embedding gather ----------------
__global__ __launch_bounds__(256) void embed_kernel(const int* __restrict__ x,
                                                    const float* __restrict__ emb,
                                                    unsigned short* __restrict__ Xemb) {
  int row = blockIdx.x;        // t*64 + b
  int t = row >> 6, b = row & 63;
  int tok = x[(size_t)b * Tn + t];
  f32x4 v = ((const f32x4*)(emb + (size_t)tok * Hn))[threadIdx.x];
  u16x4 p;
#pragma unroll
  for (int u = 0; u < 4; ++u) p[u] = f2bf(v[u]);
  ((u16x4*)(Xemb + (size_t)row * Hn))[threadIdx.x] = p;
}

// ---------------- init hmask (both parities) ----------------
__global__ __launch_bounds__(256) void init_hmask_kernel(const float* __restrict__ h0,
                                                         unsigned short* __restrict__ hmask) {
  int i = blockIdx.x * blockDim.x + threadIdx.x;
  unsigned short us = f2bf(h0[i]);
  hmask[i] = us;
  hmask[Ln * Bn * Hn + i] = us;
}

// ---------------- persistent wavefront: W in regs, custom grid barrier ----------------
// grid 256 blocks (forced 1/CU by VGPR>256): cell = bid>>6, bn = bid&63
__global__ __launch_bounds__(256, 1) void wavefront_kernel(
    const char* __restrict__ Wlay, const float* __restrict__ biasF,
    const char* __restrict__ Xemb,
    unsigned short* __restrict__ hmask, unsigned short* __restrict__ hfresh,
    const int* __restrict__ len, const int* __restrict__ rankp,
    const float* __restrict__ h0, const float* __restrict__ c0,
    float* __restrict__ outp, float* __restrict__ hF, float* __restrict__ cF,
    int* __restrict__ barc, int* __restrict__ barg) {
  __shared__ char smem[65536];
  int tid = threadIdx.x, bid = blockIdx.x;
  int cell = bid >> 6, bn = bid & 63;
  int w = tid >> 6, lane = tid & 63, l15 = lane & 15, lk = lane >> 4;

  // one-time W preload: 256 KB/block -> 256 VGPR/thread (static-indexed)
  bf16x8 wreg[64];
  {
    const char* wrow = Wlay + ((size_t)((cell * 64 + bn) * 64 + w * 16 + l15)) * 4096 + lk * 16;
#pragma unroll
    for (int i = 0; i < 64; ++i)
      wreg[i] = *(const bf16x8*)(wrow + i * 64);
  }

  int r = tid >> 2;
  int c0i = (tid & 3) << 2;
  int hc = bn * 16 + c0i;
  const float* bias = biasF + cell * GN;
  f32x4 bI = *(const f32x4*)(bias + hc);
  f32x4 bF = *(const f32x4*)(bias + 1024 + hc);
  f32x4 bG = *(const f32x4*)(bias + 2048 + hc);
  f32x4 bO = *(const f32x4*)(bias + 3072 + hc);
  int lenr = len[r];
  int rnkr = rankp[r];
  f32x4 hold = *(const f32x4*)(h0 + ((size_t)cell * Bn + r) * Hn + hc);
  f32x4 cold = *(const f32x4*)(c0 + ((size_t)cell * Bn + r) * Hn + hc);

#define STAGE(BUFO, BASE)                                                     \
  {                                                                           \
    _Pragma("unroll")                                                         \
    for (int i_ = 0; i_ < 8; ++i_) {                                          \
      int o_ = i_ * 4096 + tid * 16;                                          \
      int row_ = o_ >> 9, win_ = o_ & 511;                                    \
      gload16((BASE) + (size_t)row_ * 2048 + (win_ ^ ((row_ & 7) << 4)),      \
              smem + (BUFO) + o_);                                            \
    }                                                                         \
  }

  for (int d = 0; d < NDIAG; ++d) {
    int t = d - cell;
    if (t >= 0 && t < Tn) {
      int p = d & 1;
      const char* inbase = (cell == 0)
          ? (Xemb + (size_t)t * (Bn * Hn * 2))
          : (const char*)(hfresh + ((size_t)p * Ln + (cell - 1)) * (Bn * Hn));
      const char* hmbase = (const char*)(hmask + ((size_t)p * Ln + cell) * (Bn * Hn));
      unsigned short* hmW = hmask + ((size_t)(p ^ 1) * Ln + cell) * (Bn * Hn);
      unsigned short* hfW = hfresh + ((size_t)(p ^ 1) * Ln + cell) * (Bn * Hn);

      f32x4 acc[4] = {};
      STAGE(0, inbase);
#pragma unroll
      for (int kc = 0; kc < 8; ++kc) {
        __syncthreads();
        if (kc < 7) {
          const char* nb = (kc + 1 < 4) ? (inbase + (kc + 1) * 512)
                                        : (hmbase + (kc + 1 - 4) * 512);
          STAGE(((kc + 1) & 1) * 32768, nb);
        }
        int bufo = (kc & 1) * 32768;
#pragma unroll
        for (int ksl = 0; ksl < 8; ++ksl) {
          int kb = ksl * 64 + lk * 16;
#pragma unroll
          for (int mi = 0; mi < 4; ++mi) {
            int row = mi * 16 + l15;
            bf16x8 afr = *(const bf16x8*)(smem + bufo + row * 512 + (kb ^ ((row & 7) << 4)));
            acc[mi] = __builtin_amdgcn_mfma_f32_16x16x32_bf16(afr, wreg[kc * 8 + ksl],
                                                              acc[mi], 0, 0, 0);
          }
        }
      }

      float* smf = (float*)smem;
#pragma unroll
      for (int mi = 0; mi < 4; ++mi)
#pragma unroll
        for (int j = 0; j < 4; ++j)
          smf[w * 1024 + (mi * 16 + lk * 4 + j) * 16 + l15] = acc[mi][j];
      __syncthreads();

      f32x4 sI = *(const f32x4*)(smf + r * 16 + c0i);
      f32x4 sF = *(const f32x4*)(smf + 1024 + r * 16 + c0i);
      f32x4 sG = *(const f32x4*)(smf + 2048 + r * 16 + c0i);
      f32x4 sO = *(const f32x4*)(smf + 3072 + r * 16 + c0i);
      bool msk = (t < lenr);
      f32x4 hx;
#pragma unroll
      for (int u = 0; u < 4; ++u) {
        float iv = sigmf(sI[u] + bI[u]);
        float fv = sigmf(sF[u] + bF[u]);
        float gv = tanhf(sG[u] + bG[u]);
        float ov = sigmf(sO[u] + bO[u]);
        float cc = fv * cold[u] + iv * gv;
        float hh = ov * tanhf(cc);
        hx[u] = hh;
        cold[u] = msk ? cc : cold[u];
        hold[u] = msk ? hh : hold[u];
      }
      u16x4 hb, xb;
#pragma unroll
      for (int u = 0; u < 4; ++u) { hb[u] = f2bf(hold[u]); xb[u] = f2bf(hx[u]); }
      *(u16x4*)(hmW + (size_t)r * Hn + hc) = hb;
      *(u16x4*)(hfW + (size_t)r * Hn + hc) = xb;
      if (cell == Ln - 1) {
        f32x4 o4;
#pragma unroll
        for (int u = 0; u < 4; ++u) o4[u] = msk ? hx[u] : 0.0f;
        *(f32x4*)(outp + ((size_t)r * Tn + t) * Hn + hc) = o4;
      }
    }

    // ---- device-scope sense-reversing grid barrier ----
    __syncthreads();
    if (tid == 0) {
      __threadfence();                                     // release: drain writes past L2
      int g = __hip_atomic_load(barg, __ATOMIC_RELAXED, __HIP_MEMORY_SCOPE_AGENT);
      if (__hip_atomic_fetch_add(barc, 1, __ATOMIC_ACQ_REL, __HIP_MEMORY_SCOPE_AGENT) == 255) {
        __hip_atomic_store(barc, 0, __ATOMIC_RELAXED, __HIP_MEMORY_SCOPE_AGENT);
        __hip_atomic_store(barg, g + 1, __ATOMIC_RELEASE, __HIP_MEMORY_SCOPE_AGENT);
      } else {
        while (__hip_atomic_load(barg, __ATOMIC_RELAXED, __HIP_MEMORY_SCOPE_AGENT) == g)
          __builtin_amdgcn_s_sleep(2);
      }
      __threadfence();                                     // acquire: invalidate L1/L2
    }
    __syncthreads();
  }

  // final state writeback with rank permutation (state lived in registers)
  *(f32x4*)(hF + ((size_t)cell * Bn + rnkr) * Hn + hc) = hold;
  *(f32x4*)(cF + ((size_t)cell * Bn + rnkr) * Hn + hc) = cold;
#undef STAGE
}

extern "C" void kernel_launch(void* const* d_in, const int* in_sizes, int n_in,
                              void* d_out, int out_size, void* d_ws, size_t ws_size,
                              hipStream_t stream) {
  const int*   x   = (const int*)d_in[0];
  const float* h0  = (const float*)d_in[1];
  const float* c0  = (const float*)d_in[2];
  const float* emb = (const float*)d_in[3];
  const float* Wih = (const float*)d_in[4];
  const float* Whh = (const float*)d_in[5];
  const float* bih = (const float*)d_in[6];
  const float* bhh = (const float*)d_in[7];
  float* out = (float*)d_out;

  char* ws = (char*)d_ws;
  unsigned short* Wlay  = (unsigned short*)ws;                   // 67108864 B
  float*          biasF = (float*)(ws + 67108864);               // 65536 B
  unsigned short* Xemb  = (unsigned short*)(ws + 67174400);      // 67108864 B
  unsigned short* hmask = (unsigned short*)(ws + 134283264);     // 1048576 B (2 parities)
  unsigned short* hfresh= (unsigned short*)(ws + 135331840);     // 1048576 B
  int*            leni  = (int*)(ws + 136380416);
  int*            ranki = (int*)(ws + 136380672);
  int*            barc  = (int*)(ws + 136380928);                // barrier count
  int*            barg  = (int*)(ws + 136381184);                // barrier generation (separate line)

  prep_kernel<<<1, 64, 0, stream>>>(x, leni, ranki, barc, barg);
  bias_kernel<<<64, 256, 0, stream>>>(bih, bhh, biasF);
  cast_w_kernel<<<32768, 256, 0, stream>>>(Wih, Whh, Wlay);
  embed_kernel<<<Tn * Bn, 256, 0, stream>>>(x, emb, Xemb);
  init_hmask_kernel<<<1024, 256, 0, stream>>>(h0, hmask);

  float* hFbase = out + (size_t)Bn * Tn * Hn;
  float* cFbase = hFbase + (size_t)Ln * Bn * Hn;

  wavefront_kernel<<<256, 256, 0, stream>>>(
      (const char*)Wlay, biasF, (const char*)Xemb, hmask, hfresh,
      leni, ranki, h0, c0, out, hFbase, cFbase, barc, barg);
}

// Round 6
// 4840.142 us; speedup vs baseline: 9.2953x; 3.3211x over previous
//
#include <hip/hip_runtime.h>
#include <hip/hip_bf16.h>
#include <stdint.h>

#define Bn 64
#define Tn 512
#define Hn 1024
#define Ln 4
#define GN 4096   // 4*H
#define NDIAG (Tn + Ln - 1)

typedef __attribute__((ext_vector_type(8))) short bf16x8;
typedef __attribute__((ext_vector_type(4))) float f32x4;
typedef __attribute__((ext_vector_type(4))) unsigned short u16x4;

__device__ __forceinline__ unsigned short f2bf(float f) {
  union { float f; unsigned u; } v; v.f = f;
  return (unsigned short)((v.u + 0x7FFFu + ((v.u >> 16) & 1u)) >> 16);
}

// cached (normal) global->LDS 16B
__device__ __forceinline__ void gload16(const void* g, void* l) {
  __builtin_amdgcn_global_load_lds((const __attribute__((address_space(1))) void*)g,
                                   (__attribute__((address_space(3))) void*)l, 16, 0, 0);
}
// device-coherent global->LDS 16B: aux = sc0|sc1 (CPol GLC=1 | SCC=16) -> bypass L1/L2, read LLC
__device__ __forceinline__ void gload16c(const void* g, void* l) {
  __builtin_amdgcn_global_load_lds((const __attribute__((address_space(1))) void*)g,
                                   (__attribute__((address_space(3))) void*)l, 16, 0, 17);
}

__device__ __forceinline__ float sigmf(float x) { return 1.0f / (1.0f + expf(-x)); }

// ---------------- prep: lengths + stable descending rank + barrier state reset ----------------
__global__ __launch_bounds__(256) void prep_kernel(const int* __restrict__ x, int* __restrict__ len,
                                                   int* __restrict__ rank, int* __restrict__ arrive,
                                                   int* __restrict__ gen) {
  __shared__ int sl[Bn];
  int t = threadIdx.x;
  arrive[t] = 0;                  // 256 slots cleared (deterministic each call)
  if (t == 0) *gen = 0;
  if (t < Bn) {
    int cnt = 0;
    const int* row = x + (size_t)t * Tn;
    for (int i = 0; i < Tn; ++i) cnt += (row[i] > 0) ? 1 : 0;
    sl[t] = cnt;
  }
  __syncthreads();
  if (t < Bn) {
    int Lb = sl[t], r = 0;
    for (int j = 0; j < Bn; ++j) {
      int lj = sl[j];
      r += ((lj > Lb) || (lj == Lb && j < t)) ? 1 : 0;
    }
    len[t] = Lb;
    rank[t] = r;
  }
}

// ---------------- bias fold ----------------
__global__ void bias_kernel(const float* __restrict__ bih, const float* __restrict__ bhh,
                            float* __restrict__ bias) {
  int i = blockIdx.x * blockDim.x + threadIdx.x;
  if (i < Ln * GN) bias[i] = bih[i] + bhh[i];
}

// ---------------- cast + permute weights into W_cat block layout ----------------
// Wlay[l][n][k]: n = bn*64 + j, j = strip*16 + hcl
// gate row g = strip*1024 + bn*16 + hcl ; k<1024 -> Wih[g][k], k>=1024 -> Whh[g][k-1024]
__global__ __launch_bounds__(256) void cast_w_kernel(const float* __restrict__ Wih,
                                                     const float* __restrict__ Whh,
                                                     unsigned short* __restrict__ Wlay) {
  size_t i = (size_t)blockIdx.x * blockDim.x + threadIdx.x; // (l, n, k4)
  int k4 = (int)(i & 511);
  int n  = (int)((i >> 9) & 4095);
  int l  = (int)(i >> 21);
  int bn = n >> 6, j = n & 63;
  int strip = j >> 4, hcl = j & 15;
  int g = strip * 1024 + bn * 16 + hcl;
  int k = k4 * 4;
  f32x4 v;
  if (k < 1024) v = *(const f32x4*)(Wih + ((size_t)l * GN + g) * Hn + k);
  else          v = *(const f32x4*)(Whh + ((size_t)l * GN + g) * Hn + (k - 1024));
  u16x4 pv;
#pragma unroll
  for (int u = 0; u < 4; ++u) pv[u] = f2bf(v[u]);
  *(u16x4*)(Wlay + i * 4) = pv;
}

// ---------------- embedding gather ----------------
__global__ __launch_bounds__(256) void embed_kernel(const int* __restrict__ x,
                                                    const float* __restrict__ emb,
                                                    unsigned short* __restrict__ Xemb) {
  int row = blockIdx.x;        // t*64 + b
  int t = row >> 6, b = row & 63;
  int tok = x[(size_t)b * Tn + t];
  f32x4 v = ((const f32x4*)(emb + (size_t)tok * Hn))[threadIdx.x];
  u16x4 p;
#pragma unroll
  for (int u = 0; u < 4; ++u) p[u] = f2bf(v[u]);
  ((u16x4*)(Xemb + (size_t)row * Hn))[threadIdx.x] = p;
}

// ---------------- init hmask (both parities) ----------------
__global__ __launch_bounds__(256) void init_hmask_kernel(const float* __restrict__ h0,
                                                         unsigned short* __restrict__ hmask) {
  int i = blockIdx.x * blockDim.x + threadIdx.x;
  unsigned short us = f2bf(h0[i]);
  hmask[i] = us;
  hmask[Ln * Bn * Hn + i] = us;
}

// stage one 16KB chunk: 64 rows x 256B window at byte-col p*256 of 2048B rows
__device__ __forceinline__ void stage_chunk(const char* base, int p, char* lbuf, int tid, bool coh) {
#pragma unroll
  for (int j = 0; j < 2; ++j) {
    int o = j * 8192 + tid * 16;
    int row = o >> 8, win = o & 255;
    const char* src = base + (size_t)row * 2048 + p * 256 + (win ^ ((row & 7) << 4));
    if (coh) gload16c(src, lbuf + o);
    else     gload16(src, lbuf + o);
  }
}

// ---------------- persistent wavefront: W in regs, fence-free coherent protocol ----------------
// grid 256 blocks x 512 threads (8 waves = 4 gate strips x 2 K-halves), 2 waves/SIMD
// cell = (bid&7)>>1 (XCD-paired), bn = (bid&1)*32 + (bid>>3)
__global__ __launch_bounds__(512, 2) void wavefront_kernel(
    const char* __restrict__ Wlay, const float* __restrict__ biasF,
    const char* __restrict__ Xemb,
    unsigned short* __restrict__ hmask, unsigned short* __restrict__ hfresh,
    const int* __restrict__ len, const int* __restrict__ rankp,
    const float* __restrict__ h0, const float* __restrict__ c0,
    float* __restrict__ outp, float* __restrict__ hF, float* __restrict__ cF,
    int* __restrict__ arrive, int* __restrict__ gen) {
  __shared__ char smem[65536];   // 4 staging bufs (kh,parity) 16KB each; exchange reuses par0 bufs
  int tid = threadIdx.x, bid = blockIdx.x;
  int cell = (bid & 7) >> 1;
  int bn = (bid & 1) * 32 + (bid >> 3);
  int w = tid >> 6, lane = tid & 63, l15 = lane & 15, lk = lane >> 4;
  int kh = w >> 2, s = w & 3;

  // one-time W preload: wave (s,kh) holds rows s*16+l15, K-half kh -> 32 bf16x8 = 128 VGPR
  bf16x8 wreg[32];
  {
    const char* wrow = Wlay + ((size_t)((cell * 64 + bn) * 64 + s * 16 + l15)) * 4096
                       + kh * 2048 + lk * 16;
#pragma unroll
    for (int i = 0; i < 32; ++i)
      wreg[i] = *(const bf16x8*)(wrow + i * 64);
  }

  // per-thread epilogue state (threads 0-255 only)
  int r = tid >> 2;
  int c0i = (tid & 3) << 2;
  int hc = bn * 16 + c0i;
  f32x4 bI = {}, bF = {}, bG = {}, bO = {}, hold = {}, cold = {};
  int lenr = 0, rnkr = 0;
  if (tid < 256) {
    const float* bias = biasF + cell * GN;
    bI = *(const f32x4*)(bias + hc);
    bF = *(const f32x4*)(bias + 1024 + hc);
    bG = *(const f32x4*)(bias + 2048 + hc);
    bO = *(const f32x4*)(bias + 3072 + hc);
    lenr = len[r];
    rnkr = rankp[r];
    hold = *(const f32x4*)(h0 + ((size_t)cell * Bn + r) * Hn + hc);
    cold = *(const f32x4*)(c0 + ((size_t)cell * Bn + r) * Hn + hc);
  }

  for (int d = 0; d < NDIAG; ++d) {
    int t = d - cell;
    if (t >= 0 && t < Tn) {
      int p = d & 1;
      bool cohLo = (cell != 0);
      const char* inbase = (cell == 0)
          ? (Xemb + (size_t)t * (Bn * Hn * 2))
          : (const char*)(hfresh + ((size_t)p * Ln + (cell - 1)) * (Bn * Hn));
      const char* hmbase = (const char*)(hmask + ((size_t)p * Ln + cell) * (Bn * Hn));
      unsigned short* hmW = hmask + ((size_t)(p ^ 1) * Ln + cell) * (Bn * Hn);
      unsigned short* hfW = hfresh + ((size_t)(p ^ 1) * Ln + cell) * (Bn * Hn);

      f32x4 acc[4] = {};
      stage_chunk(inbase, 0, smem + 0 * 16384, tid, cohLo);       // (kh0, par0)
      stage_chunk(hmbase, 0, smem + 2 * 16384, tid, true);        // (kh1, par0)
#pragma unroll
      for (int ph = 0; ph < 8; ++ph) {
        __syncthreads();                 // phase ph staged; compute ph-1 done
        if (ph < 7) {
          int par = (ph + 1) & 1;
          stage_chunk(inbase, ph + 1, smem + (0 * 2 + par) * 16384, tid, cohLo);
          stage_chunk(hmbase, ph + 1, smem + (1 * 2 + par) * 16384, tid, true);
        }
        const char* lb = smem + (kh * 2 + (ph & 1)) * 16384;
#pragma unroll
        for (int ksl = 0; ksl < 4; ++ksl) {
#pragma unroll
          for (int mi = 0; mi < 4; ++mi) {
            int row = mi * 16 + l15;
            bf16x8 afr = *(const bf16x8*)(lb + row * 256 + ((ksl * 64 + lk * 16) ^ ((row & 7) << 4)));
            acc[mi] = __builtin_amdgcn_mfma_f32_16x16x32_bf16(afr, wreg[ph * 4 + ksl],
                                                              acc[mi], 0, 0, 0);
          }
        }
      }

      // exchange: kh half -> par0 buf regions ([0,16K) and [32K,48K)), strip-major [64][16] f32
      float* ex = (float*)smem + kh * 8192 + s * 1024;
#pragma unroll
      for (int mi = 0; mi < 4; ++mi)
#pragma unroll
        for (int j = 0; j < 4; ++j)
          ex[(mi * 16 + lk * 4 + j) * 16 + l15] = acc[mi][j];
      __syncthreads();

      if (tid < 256) {
        float* smf = (float*)smem;
        f32x4 sI = *(const f32x4*)(smf + r * 16 + c0i)        + *(const f32x4*)(smf + 8192 + r * 16 + c0i);
        f32x4 sF = *(const f32x4*)(smf + 1024 + r * 16 + c0i) + *(const f32x4*)(smf + 9216 + r * 16 + c0i);
        f32x4 sG = *(const f32x4*)(smf + 2048 + r * 16 + c0i) + *(const f32x4*)(smf + 10240 + r * 16 + c0i);
        f32x4 sO = *(const f32x4*)(smf + 3072 + r * 16 + c0i) + *(const f32x4*)(smf + 11264 + r * 16 + c0i);
        bool msk = (t < lenr);
        f32x4 hx;
#pragma unroll
        for (int u = 0; u < 4; ++u) {
          float iv = sigmf(sI[u] + bI[u]);
          float fv = sigmf(sF[u] + bF[u]);
          float gv = tanhf(sG[u] + bG[u]);
          float ov = sigmf(sO[u] + bO[u]);
          float cc = fv * cold[u] + iv * gv;
          float hh = ov * tanhf(cc);
          hx[u] = hh;
          cold[u] = msk ? cc : cold[u];
          hold[u] = msk ? hh : hold[u];
        }
        unsigned hb01 = (unsigned)f2bf(hold[0]) | ((unsigned)f2bf(hold[1]) << 16);
        unsigned hb23 = (unsigned)f2bf(hold[2]) | ((unsigned)f2bf(hold[3]) << 16);
        unsigned xb01 = (unsigned)f2bf(hx[0]) | ((unsigned)f2bf(hx[1]) << 16);
        unsigned xb23 = (unsigned)f2bf(hx[2]) | ((unsigned)f2bf(hx[3]) << 16);
        unsigned* hm32 = (unsigned*)(hmW + (size_t)r * Hn + hc);
        unsigned* hf32p = (unsigned*)(hfW + (size_t)r * Hn + hc);
        __hip_atomic_store(hm32,     hb01, __ATOMIC_RELAXED, __HIP_MEMORY_SCOPE_AGENT);
        __hip_atomic_store(hm32 + 1, hb23, __ATOMIC_RELAXED, __HIP_MEMORY_SCOPE_AGENT);
        __hip_atomic_store(hf32p,     xb01, __ATOMIC_RELAXED, __HIP_MEMORY_SCOPE_AGENT);
        __hip_atomic_store(hf32p + 1, xb23, __ATOMIC_RELAXED, __HIP_MEMORY_SCOPE_AGENT);
        if (cell == Ln - 1) {
          f32x4 o4;
#pragma unroll
          for (int u = 0; u < 4; ++u) o4[u] = msk ? hx[u] : 0.0f;
          *(f32x4*)(outp + ((size_t)r * Tn + t) * Hn + hc) = o4;
        }
      }
    }

    // ---- store-based distributed barrier (no fences, no RMW) ----
    __syncthreads();    // drains all waves' vmcnt -> agent stores are at LLC
    if (tid == 0)
      __hip_atomic_store(&arrive[bid], d + 1, __ATOMIC_RELAXED, __HIP_MEMORY_SCOPE_AGENT);
    if (bid == 0) {
      if (tid < 256) {
        while (__hip_atomic_load(&arrive[tid], __ATOMIC_RELAXED, __HIP_MEMORY_SCOPE_AGENT) <= d)
          __builtin_amdgcn_s_sleep(1);
      }
      __syncthreads();
      if (tid == 0)
        __hip_atomic_store(gen, d + 1, __ATOMIC_RELAXED, __HIP_MEMORY_SCOPE_AGENT);
    } else {
      if (tid == 0) {
        while (__hip_atomic_load(gen, __ATOMIC_RELAXED, __HIP_MEMORY_SCOPE_AGENT) <= d)
          __builtin_amdgcn_s_sleep(1);
      }
      __syncthreads();
    }
    asm volatile("" ::: "memory");
  }

  // final state writeback with rank permutation (state lived in registers)
  if (tid < 256) {
    *(f32x4*)(hF + ((size_t)cell * Bn + rnkr) * Hn + hc) = hold;
    *(f32x4*)(cF + ((size_t)cell * Bn + rnkr) * Hn + hc) = cold;
  }
}

extern "C" void kernel_launch(void* const* d_in, const int* in_sizes, int n_in,
                              void* d_out, int out_size, void* d_ws, size_t ws_size,
                              hipStream_t stream) {
  const int*   x   = (const int*)d_in[0];
  const float* h0  = (const float*)d_in[1];
  const float* c0  = (const float*)d_in[2];
  const float* emb = (const float*)d_in[3];
  const float* Wih = (const float*)d_in[4];
  const float* Whh = (const float*)d_in[5];
  const float* bih = (const float*)d_in[6];
  const float* bhh = (const float*)d_in[7];
  float* out = (float*)d_out;

  char* ws = (char*)d_ws;
  unsigned short* Wlay  = (unsigned short*)ws;                   // 67108864 B
  float*          biasF = (float*)(ws + 67108864);               // 65536 B
  unsigned short* Xemb  = (unsigned short*)(ws + 67174400);      // 67108864 B
  unsigned short* hmask = (unsigned short*)(ws + 134283264);     // 1048576 B (2 parities)
  unsigned short* hfresh= (unsigned short*)(ws + 135331840);     // 1048576 B
  int*            leni  = (int*)(ws + 136380416);
  int*            ranki = (int*)(ws + 136380672);
  int*            arrv  = (int*)(ws + 136380928);                // 256 arrive slots
  int*            genp  = (int*)(ws + 136381952);                // generation word

  prep_kernel<<<1, 256, 0, stream>>>(x, leni, ranki, arrv, genp);
  bias_kernel<<<64, 256, 0, stream>>>(bih, bhh, biasF);
  cast_w_kernel<<<32768, 256, 0, stream>>>(Wih, Whh, Wlay);
  embed_kernel<<<Tn * Bn, 256, 0, stream>>>(x, emb, Xemb);
  init_hmask_kernel<<<1024, 256, 0, stream>>>(h0, hmask);

  float* hFbase = out + (size_t)Bn * Tn * Hn;
  float* cFbase = hFbase + (size_t)Ln * Bn * Hn;

  wavefront_kernel<<<256, 512, 0, stream>>>(
      (const char*)Wlay, biasF, (const char*)Xemb, hmask, hfresh,
      leni, ranki, h0, c0, out, hFbase, cFbase, arrv, genp);
}